// Round 1
// 70.339 us; speedup vs baseline: 1.0637x; 1.0637x over previous
//
#include <hip/hip_runtime.h>
#include <math.h>

#define LOG2PI 1.8378770664093453f
#define NSTATES 136
#define NROWS 5120   // 512 * 10
#define DIM 64
#define NCLUST 16
#define NBLOCKS 640
#define NEG_BIG -1e30f
#define INV_SQRT2 0.70710678118654752f

// ---------------------------------------------------------------------------
// Fused kernel: 640 blocks x 512 threads (8 waves), ONE row per wave.
//  Prologue (per block, redundant, overlapped across 640 blocks):
//    stage mu (transposed) + pi + A/B into LDS; wave 3 computes pi-softmax
//    denom while tids<136 compute per-state {c1, nb2, inv_sig}; finalize
//    k0s/k1s in LDS. Waves 4-7 idle through the prologue (~0.4us).
//  Main (per wave, 1 row):
//    Phase A: colz[c] = z . mu[:,c] (16 cols) + |z|^2 via lane=(chunk,c)
//             float4 partial dots + shfl_xor(16,32).
//    Phase B: 3 states/lane; dynamic shfl gathers colz[A],colz[B];
//             interval CDF via 0.5*(erf(a)+erf(b))  (erff, not erfcf).
//    LSE: two-pass (max tree then sum tree) -> 3 exps/row, no dependent
//         exp chain in the reduction rounds.
//  Epilogue: one float per block -> partials[bid] (no atomics, no pre-zero).
// ---------------------------------------------------------------------------
__global__ __launch_bounds__(512) void latent_fused_kernel(
    const float* __restrict__ z,    // [5120*64]
    const float* __restrict__ mu,   // [64*16] row-major [d][c]
    const float* __restrict__ pi,   // [136]
    const int* __restrict__ A, const int* __restrict__ B,
    float* __restrict__ partials)   // [640]
{
    __shared__ float muT[NCLUST][68];   // transposed, pad 68: float4 reads -> 2-way conflicts only (free)
    __shared__ float pis[NSTATES];
    __shared__ float4 k0s[NSTATES];     // {c1, nb2, recip, sd/sqrt2}
    __shared__ float2 k1s[NSTATES];     // {lcomb, lzero}
    __shared__ int2  abs_[NSTATES];
    __shared__ float sm_m, sm_z;
    __shared__ float redbuf[8];

    int tid = threadIdx.x;
    #pragma unroll
    for (int i = tid; i < DIM * NCLUST; i += 512) {
        muT[i & 15][i >> 4] = mu[i];    // coalesced read, conflict-free scatter
    }
    if (tid < NSTATES) {
        pis[tid] = pi[tid];
        abs_[tid] = make_int2(A[tid], B[tid]);
    }
    __syncthreads();

    // ---- per-state constants (redundant per block) ----
    float c1 = 0.f, nb2 = 0.f, iv = 0.f;
    if (tid < NSTATES) {
        int2 ab = abs_[tid];
        #pragma unroll 8
        for (int d = 0; d < DIM; ++d) {
            float mA = muT[ab.x][d];
            float mB = muT[ab.y][d];
            float a1 = mB - mA;
            c1  += a1 * mB;
            nb2 += mB * mB;
            iv  += a1 * a1;
        }
    } else if (tid >= 192 && tid < 256) { // wave 3: pi-softmax denom
        int l = tid - 192;
        float m = NEG_BIG;
        for (int i = l; i < NSTATES; i += 64) m = fmaxf(m, pis[i]);
        #pragma unroll
        for (int d = 1; d < 64; d <<= 1) m = fmaxf(m, __shfl_xor(m, d));
        float s = 0.f;
        for (int i = l; i < NSTATES; i += 64) s += expf(pis[i] - m);
        #pragma unroll
        for (int d = 1; d < 64; d <<= 1) s += __shfl_xor(s, d);
        if (l == 0) { sm_m = m; sm_z = s; }
    }
    __syncthreads();
    if (tid < NSTATES) {
        float recip  = (iv == 0.f) ? 0.f : 1.f / iv;
        float sdq    = sqrtf(iv + 1e-12f) * INV_SQRT2;   // sd / sqrt(2)
        float lp     = logf(expf(pis[tid] - sm_m) / sm_z + 1e-12f);
        k0s[tid] = make_float4(c1, nb2, recip, sdq);
        k1s[tid] = make_float2(lp - 31.5f * LOG2PI - 0.5f * logf(iv + 1e-12f),
                               lp - 32.0f * LOG2PI);
    }
    __syncthreads();

    // ---- main: one row per wave ----
    int w = tid >> 6, lane = tid & 63;
    int chunk = lane >> 4, c = lane & 15;
    int r = blockIdx.x * 8 + w;           // row in [0, 5120)

    // ---- Phase A: column dots ----
    const float4* zp = (const float4*)(z + (size_t)r * DIM + chunk * 16);
    const float4* mp = (const float4*)(&muT[c][chunk * 16]);
    float dotc = 0.f, zn = 0.f;
    #pragma unroll
    for (int i = 0; i < 4; ++i) {
        float4 z4 = zp[i];
        float4 m4 = mp[i];
        dotc += z4.x * m4.x + z4.y * m4.y + z4.z * m4.z + z4.w * m4.w;
        zn   += z4.x * z4.x + z4.y * z4.y + z4.z * z4.z + z4.w * z4.w;
    }
    dotc += __shfl_xor(dotc, 16);
    dotc += __shfl_xor(dotc, 32);
    zn   += __shfl_xor(zn, 16);
    zn   += __shfl_xor(zn, 32);
    // lane l holds colz[l & 15]; zn is full |z|^2 in every lane

    // ---- Phase B: per-state values ----
    float vals[3];
    #pragma unroll
    for (int it = 0; it < 3; ++it) {
        int s = it * 64 + lane;
        bool valid = (s < NSTATES);
        int ss = valid ? s : 0;
        int2 ab = abs_[ss];
        float4 K0 = k0s[ss];
        float2 K1 = k1s[ss];
        float cza = __shfl(dotc, ab.x);    // colz[A[s]]
        float czb = __shfl(dotc, ab.y);    // colz[B[s]]
        float dot = czb - cza - K0.x;      // a1 . a2
        float sq  = zn - 2.f * czb + K0.y; // |a2|^2
        float mu_ = -dot * K0.z;
        float t   = -sq + dot * dot * K0.z;
        // ndtr((1-mu)*sd) - ndtr(-mu*sd) == 0.5*(erf((1-mu)*sd/rt2) + erf(mu*sd/rt2))
        float dcdf = 0.5f * (erff((1.f - mu_) * K0.w) + erff(mu_ * K0.w));
        float v_n = K1.x + 0.5f * t + logf(dcdf + 1e-12f);
        float v_z = K1.y - 0.5f * sq;
        float v = (K0.z == 0.f) ? v_z : v_n;
        vals[it] = valid ? v : NEG_BIG;
    }

    // ---- two-pass wave logsumexp: max tree, then sum tree ----
    float m = fmaxf(fmaxf(vals[0], vals[1]), vals[2]);
    #pragma unroll
    for (int d = 1; d < 64; d <<= 1) m = fmaxf(m, __shfl_xor(m, d));
    float s = expf(vals[0] - m) + expf(vals[1] - m) + expf(vals[2] - m);
    #pragma unroll
    for (int d = 1; d < 64; d <<= 1) s += __shfl_xor(s, d);

    if (lane == 0) redbuf[w] = m + logf(s);
    __syncthreads();
    if (tid == 0) {
        float t = 0.f;
        #pragma unroll
        for (int i = 0; i < 8; ++i) t += redbuf[i];
        partials[blockIdx.x] = t;
    }
}

// ---------------------------------------------------------------------------
// Tail: sum 640 partials -> out[0] = sum / 5120. One tiny block.
// ---------------------------------------------------------------------------
__global__ __launch_bounds__(256) void final_reduce_kernel(
    const float* __restrict__ partials, float* __restrict__ out)
{
    __shared__ float rb[4];
    int tid = threadIdx.x;
    float s = 0.f;
    for (int i = tid; i < NBLOCKS; i += 256) s += partials[i];
    #pragma unroll
    for (int d = 1; d < 64; d <<= 1) s += __shfl_xor(s, d);
    if ((tid & 63) == 0) rb[tid >> 6] = s;
    __syncthreads();
    if (tid == 0) out[0] = (rb[0] + rb[1] + rb[2] + rb[3]) * (1.0f / (float)NROWS);
}

extern "C" void kernel_launch(void* const* d_in, const int* in_sizes, int n_in,
                              void* d_out, int out_size, void* d_ws, size_t ws_size,
                              hipStream_t stream) {
    const float* z  = (const float*)d_in[0];
    const float* mu = (const float*)d_in[1];
    const float* pi = (const float*)d_in[2];
    const int*   A  = (const int*)d_in[3];
    const int*   B  = (const int*)d_in[4];
    float* out = (float*)d_out;
    float* partials = (float*)d_ws;       // 640 * 4 B

    latent_fused_kernel<<<NBLOCKS, 512, 0, stream>>>(z, mu, pi, A, B, partials);
    final_reduce_kernel<<<1, 256, 0, stream>>>(partials, out);
}

// Round 2
// 69.924 us; speedup vs baseline: 1.0700x; 1.0059x over previous
//
#include <hip/hip_runtime.h>
#include <math.h>

#define LOG2PI 1.8378770664093453f
#define NSTATES 136
#define NROWS 5120   // 512 * 10
#define DIM 64
#define NCLUST 16
#define NBLOCKS 640
#define NEG_BIG -1e30f
#define INV_SQRT2 0.70710678118654752f

// Fast erf: Abramowitz & Stegun 7.1.26, |err| <= 1.5e-7.
// rcp + 5 FMA + v_exp_f32: ~12 VALU ops vs OCML erff's ~30 (branchy).
// Large |x|: exp(-x^2) underflows to 0 -> returns +-1 exactly. Feeds
// log(dcdf + 1e-12), so 1e-7 abs error is invisible at the output.
__device__ __forceinline__ float erf_fast(float x) {
    float ax = fabsf(x);
    float t = __builtin_amdgcn_rcpf(fmaf(0.3275911f, ax, 1.0f)); // ~1ulp, fine
    float p = fmaf(1.061405429f, t, -1.453152027f);
    p = fmaf(p, t, 1.421413741f);
    p = fmaf(p, t, -0.284496736f);
    p = fmaf(p, t, 0.254829592f);
    p *= t;
    float e = __expf(-ax * ax);          // v_exp_f32 path
    float r = fmaf(-p, e, 1.0f);
    return copysignf(r, x);
}

// ---------------------------------------------------------------------------
// Fused kernel: 640 blocks x 512 threads (8 waves), ONE row per wave.
//  Prologue (per block, redundant, all 640 blocks co-resident so paid once
//  in wall-clock): stage mu (transposed) + pi + A/B into LDS; wave 3
//  computes pi-softmax denom while tids<136 compute per-state constants
//  via float4 LDS reads (16 iters, not 64).
//  Main (per wave, 1 row):
//    Phase A: colz[c] = z . mu[:,c] (16 cols) + |z|^2 via lane=(chunk,c)
//             float4 partial dots + shfl_xor(16,32).
//    Phase B: 3 states/lane; dynamic shfl gathers colz[A],colz[B];
//             interval CDF via 0.5*(erf_fast(a)+erf_fast(b)); __logf.
//    LSE: two-pass (max tree then sum tree), __expf/__logf.
//  Epilogue: one float per block -> partials[bid] (no atomics, no pre-zero).
// ---------------------------------------------------------------------------
__global__ __launch_bounds__(512) void latent_fused_kernel(
    const float* __restrict__ z,    // [5120*64]
    const float* __restrict__ mu,   // [64*16] row-major [d][c]
    const float* __restrict__ pi,   // [136]
    const int* __restrict__ A, const int* __restrict__ B,
    float* __restrict__ partials)   // [640]
{
    __shared__ float muT[NCLUST][68];   // pad 68: row starts 16B-aligned, float4-readable
    __shared__ float pis[NSTATES];
    __shared__ float4 k0s[NSTATES];     // {c1, nb2, recip, sd/sqrt2}
    __shared__ float2 k1s[NSTATES];     // {lcomb, lzero}
    __shared__ int2  abs_[NSTATES];
    __shared__ float sm_m, sm_z;
    __shared__ float redbuf[8];

    int tid = threadIdx.x;
    #pragma unroll
    for (int i = tid; i < DIM * NCLUST; i += 512) {
        muT[i & 15][i >> 4] = mu[i];    // coalesced read, conflict-free scatter
    }
    if (tid < NSTATES) {
        pis[tid] = pi[tid];
        abs_[tid] = make_int2(A[tid], B[tid]);
    }
    __syncthreads();

    // ---- per-state constants (redundant per block) ----
    float c1 = 0.f, nb2 = 0.f, iv = 0.f;
    if (tid < NSTATES) {
        int2 ab = abs_[tid];
        const float4* rA = (const float4*)(&muT[ab.x][0]);
        const float4* rB = (const float4*)(&muT[ab.y][0]);
        #pragma unroll
        for (int d = 0; d < DIM / 4; ++d) {
            float4 mA = rA[d];
            float4 mB = rB[d];
            float a1x = mB.x - mA.x, a1y = mB.y - mA.y,
                  a1z = mB.z - mA.z, a1w = mB.w - mA.w;
            c1  += a1x * mB.x + a1y * mB.y + a1z * mB.z + a1w * mB.w;
            nb2 += mB.x * mB.x + mB.y * mB.y + mB.z * mB.z + mB.w * mB.w;
            iv  += a1x * a1x + a1y * a1y + a1z * a1z + a1w * a1w;
        }
    } else if (tid >= 192 && tid < 256) { // wave 3: pi-softmax denom
        int l = tid - 192;
        float m = NEG_BIG;
        for (int i = l; i < NSTATES; i += 64) m = fmaxf(m, pis[i]);
        #pragma unroll
        for (int d = 1; d < 64; d <<= 1) m = fmaxf(m, __shfl_xor(m, d));
        float s = 0.f;
        for (int i = l; i < NSTATES; i += 64) s += __expf(pis[i] - m);
        #pragma unroll
        for (int d = 1; d < 64; d <<= 1) s += __shfl_xor(s, d);
        if (l == 0) { sm_m = m; sm_z = s; }
    }
    __syncthreads();
    if (tid < NSTATES) {
        float recip  = (iv == 0.f) ? 0.f : 1.f / iv;
        float sdq    = sqrtf(iv + 1e-12f) * INV_SQRT2;   // sd / sqrt(2)
        float lp     = __logf(__expf(pis[tid] - sm_m) / sm_z + 1e-12f);
        k0s[tid] = make_float4(c1, nb2, recip, sdq);
        k1s[tid] = make_float2(lp - 31.5f * LOG2PI - 0.5f * __logf(iv + 1e-12f),
                               lp - 32.0f * LOG2PI);
    }
    __syncthreads();

    // ---- main: one row per wave ----
    int w = tid >> 6, lane = tid & 63;
    int chunk = lane >> 4, c = lane & 15;
    int r = blockIdx.x * 8 + w;           // row in [0, 5120)

    // ---- Phase A: column dots ----
    const float4* zp = (const float4*)(z + (size_t)r * DIM + chunk * 16);
    const float4* mp = (const float4*)(&muT[c][chunk * 16]);
    float dotc = 0.f, zn = 0.f;
    #pragma unroll
    for (int i = 0; i < 4; ++i) {
        float4 z4 = zp[i];
        float4 m4 = mp[i];
        dotc += z4.x * m4.x + z4.y * m4.y + z4.z * m4.z + z4.w * m4.w;
        zn   += z4.x * z4.x + z4.y * z4.y + z4.z * z4.z + z4.w * z4.w;
    }
    dotc += __shfl_xor(dotc, 16);
    dotc += __shfl_xor(dotc, 32);
    zn   += __shfl_xor(zn, 16);
    zn   += __shfl_xor(zn, 32);
    // lane l holds colz[l & 15]; zn is full |z|^2 in every lane

    // ---- Phase B: per-state values ----
    float vals[3];
    #pragma unroll
    for (int it = 0; it < 3; ++it) {
        int s = it * 64 + lane;
        bool valid = (s < NSTATES);
        int ss = valid ? s : 0;
        int2 ab = abs_[ss];
        float4 K0 = k0s[ss];
        float2 K1 = k1s[ss];
        float cza = __shfl(dotc, ab.x);    // colz[A[s]]
        float czb = __shfl(dotc, ab.y);    // colz[B[s]]
        float dot = czb - cza - K0.x;      // a1 . a2
        float sq  = zn - 2.f * czb + K0.y; // |a2|^2
        float mu_ = -dot * K0.z;
        float t   = -sq + dot * dot * K0.z;
        // ndtr((1-mu)*sd) - ndtr(-mu*sd) == 0.5*(erf((1-mu)*sd/rt2) + erf(mu*sd/rt2))
        float dcdf = 0.5f * (erf_fast((1.f - mu_) * K0.w) + erf_fast(mu_ * K0.w));
        float v_n = K1.x + 0.5f * t + __logf(dcdf + 1e-12f);
        float v_z = K1.y - 0.5f * sq;
        float v = (K0.z == 0.f) ? v_z : v_n;
        vals[it] = valid ? v : NEG_BIG;
    }

    // ---- two-pass wave logsumexp: max tree, then sum tree ----
    float m = fmaxf(fmaxf(vals[0], vals[1]), vals[2]);
    #pragma unroll
    for (int d = 1; d < 64; d <<= 1) m = fmaxf(m, __shfl_xor(m, d));
    float s = __expf(vals[0] - m) + __expf(vals[1] - m) + __expf(vals[2] - m);
    #pragma unroll
    for (int d = 1; d < 64; d <<= 1) s += __shfl_xor(s, d);

    if (lane == 0) redbuf[w] = m + __logf(s);
    __syncthreads();
    if (tid == 0) {
        float t = 0.f;
        #pragma unroll
        for (int i = 0; i < 8; ++i) t += redbuf[i];
        partials[blockIdx.x] = t;
    }
}

// ---------------------------------------------------------------------------
// Tail: sum 640 partials -> out[0] = sum / 5120. One tiny block.
// ---------------------------------------------------------------------------
__global__ __launch_bounds__(256) void final_reduce_kernel(
    const float* __restrict__ partials, float* __restrict__ out)
{
    __shared__ float rb[4];
    int tid = threadIdx.x;
    float s = 0.f;
    for (int i = tid; i < NBLOCKS; i += 256) s += partials[i];
    #pragma unroll
    for (int d = 1; d < 64; d <<= 1) s += __shfl_xor(s, d);
    if ((tid & 63) == 0) rb[tid >> 6] = s;
    __syncthreads();
    if (tid == 0) out[0] = (rb[0] + rb[1] + rb[2] + rb[3]) * (1.0f / (float)NROWS);
}

extern "C" void kernel_launch(void* const* d_in, const int* in_sizes, int n_in,
                              void* d_out, int out_size, void* d_ws, size_t ws_size,
                              hipStream_t stream) {
    const float* z  = (const float*)d_in[0];
    const float* mu = (const float*)d_in[1];
    const float* pi = (const float*)d_in[2];
    const int*   A  = (const int*)d_in[3];
    const int*   B  = (const int*)d_in[4];
    float* out = (float*)d_out;
    float* partials = (float*)d_ws;       // 640 * 4 B

    latent_fused_kernel<<<NBLOCKS, 512, 0, stream>>>(z, mu, pi, A, B, partials);
    final_reduce_kernel<<<1, 256, 0, stream>>>(partials, out);
}